// Round 3
// baseline (5116.832 us; speedup 1.0000x reference)
//
#include <hip/hip_runtime.h>
#include <hip/hip_bf16.h>

typedef __hip_bfloat16 bf16;

#define PER_B     6291456            // 96*65536
#define S_EL      25165824u          // 4*PER_B
#define EPS_F     1e-5f
#define SCALE_F   0.17677669529663687f   // 32^-0.5
#define LOGIT_MAX_F 4.605170185988092f   // log(100)

__device__ __forceinline__ float b2f(bf16 v){ return __bfloat162float(v); }
__device__ __forceinline__ bf16  f2b(float v){ return __float2bfloat16(v); }

// DT=0: buffers are bf16.  DT=1: buffers are fp32.
template<int DT> __device__ __forceinline__ float rdf(const void* p, size_t i){
  return DT ? ((const float*)p)[i] : b2f(((const bf16*)p)[i]);
}
template<int DT> __device__ __forceinline__ void wrf(void* p, size_t i, float v){
  if (DT) ((float*)p)[i] = v; else ((bf16*)p)[i] = f2b(v);
}

// ---------- K0: dtype detector ----------
// Sample x at even bf16 indices. If buffer is fp32, these are fp32 low halves:
// ~uniform bits -> ~24% decode to |v|>1e20 or NaN. True bf16 N(0,1): 0 hits.
__global__ __launch_bounds__(256) void k_detect(const void* __restrict__ x, int* __restrict__ flag){
  __shared__ int cnt;
  if (threadIdx.x == 0) cnt = 0;
  __syncthreads();
  float v = b2f(((const bf16*)x)[(size_t)threadIdx.x * 16]);
  int bad = (!(v == v)) || (fabsf(v) > 1e20f);
  if (bad) atomicAdd(&cnt, 1);
  __syncthreads();
  if (threadIdx.x == 0) *flag = (cnt >= 4) ? 1 : 0;
}

// ---------- K1: per-batch partial sums ----------
template<int DT>
__global__ __launch_bounds__(256) void k_stats_partial(const void* __restrict__ x,
    float* __restrict__ partials, const int* __restrict__ flag){
  if (*flag != DT) return;
  int blk = blockIdx.x;
  int b = blk >> 8, chunk = blk & 255;
  const int chunkN = PER_B / 256;
  size_t base = (size_t)b * PER_B + (size_t)chunk * chunkN;
  float s = 0.f, ss = 0.f;
  for (int i = threadIdx.x; i < chunkN; i += 256){
    float v = rdf<DT>(x, base + i); s += v; ss += v*v;
  }
  __shared__ float sh[512];
  sh[threadIdx.x] = s; sh[256 + threadIdx.x] = ss;
  __syncthreads();
  for (int st = 128; st > 0; st >>= 1){
    if (threadIdx.x < st){
      sh[threadIdx.x]     += sh[threadIdx.x + st];
      sh[256+threadIdx.x] += sh[256+threadIdx.x + st];
    }
    __syncthreads();
  }
  if (threadIdx.x == 0){ partials[blk*2] = sh[0]; partials[blk*2+1] = sh[256]; }
}

// ---------- K2: finalize mean/std + rescale/rebias ----------
// stats: [0..3]=mean, [4..7]=std, [8..391]=rescale[b*96+c], [392..775]=rebias
template<int DT>
__global__ __launch_bounds__(256) void k_stats_final(const float* __restrict__ partials,
    const void* m1w, const void* m1b, const void* m2w, const void* m2b,
    float* __restrict__ stats, const int* __restrict__ flag){
  if (*flag != DT) return;
  __shared__ float sh[512];
  __shared__ float mS[4], sS[4];
  for (int b = 0; b < 4; b++){
    sh[threadIdx.x]     = partials[(b*256+threadIdx.x)*2];
    sh[256+threadIdx.x] = partials[(b*256+threadIdx.x)*2+1];
    __syncthreads();
    for (int st = 128; st > 0; st >>= 1){
      if (threadIdx.x < st){
        sh[threadIdx.x]     += sh[threadIdx.x + st];
        sh[256+threadIdx.x] += sh[256+threadIdx.x + st];
      }
      __syncthreads();
    }
    if (threadIdx.x == 0){
      float mean = sh[0] / (float)PER_B;
      float var  = sh[256] / (float)PER_B - mean*mean;
      float stdv = sqrtf(var + EPS_F);
      mS[b] = mean; sS[b] = stdv;
      stats[b] = mean; stats[4+b] = stdv;
    }
    __syncthreads();
  }
  for (int t = threadIdx.x; t < 384; t += 256){
    int b = t / 96, c = t % 96;
    stats[8+t]   = sS[b]*rdf<DT>(m1w,c) + rdf<DT>(m1b,c);
    stats[392+t] = mS[b]*rdf<DT>(m2w,c) + rdf<DT>(m2b,c);
  }
}

// ---------- K3: rel-pos bias table, transposed [h][m][n] ----------
template<int DT>
__global__ __launch_bounds__(256) void k_bias(const void* w1, const void* b1v,
    const void* w2, const void* b2v, float* __restrict__ biasT, const int* __restrict__ flag){
  if (*flag != DT) return;
  int i = blockIdx.x >> 6, j = blockIdx.x & 63;   // i = query n, j = key m
  int dy = (i>>3) - (j>>3), dx = (i&7) - (j&7);
  float fy = (float)dy, fx = (float)dx;
  float r0 = copysignf(log1pf(fabsf(fy)), fy);
  float r1 = copysignf(log1pf(fabsf(fx)), fx);
  int t = threadIdx.x;
  float hb = fmaxf(r0*rdf<DT>(w1,t*2) + r1*rdf<DT>(w1,t*2+1) + rdf<DT>(b1v,t), 0.f);
  __shared__ float sh[256];
  for (int h = 0; h < 3; h++){
    sh[t] = hb * rdf<DT>(w2, h*256+t);
    __syncthreads();
    for (int st = 128; st > 0; st >>= 1){ if (t < st) sh[t] += sh[t+st]; __syncthreads(); }
    if (t == 0) biasT[h*4096 + j*64 + i] = sh[0] + rdf<DT>(b2v, h);
    __syncthreads();
  }
}

// ---------- K4: fused AGN: x -> xn2 (bf16), 16x16 tile + halo2, one channel/block ----------
template<int DT>
__global__ __launch_bounds__(256) void k_agn_fused(const void* __restrict__ x,
    const float* __restrict__ stats,
    const void* la1w, const void* la1b, const void* la2w, const void* la2b,
    const void* ta1w, const void* ta1b, const void* ta2w, const void* ta2b,
    const void* agnw, const void* agnb,
    bf16* __restrict__ xn2, const int* __restrict__ flag){
  if (*flag != DT) return;
  __shared__ float xs[400];   // 20x20 zero-padded
  __shared__ float ts[324];   // 18x18
  __shared__ float us[324];
  int idx = blockIdx.x;
  int tile = idx & 255; int bc = idx >> 8; int c = bc % 96; int b = bc / 96;
  int oy = (tile >> 4) << 4, ox = (tile & 15) << 4;
  float mean = stats[b], sd = stats[4+b];
  size_t xbase = ((size_t)bc) << 16;
  for (int it = threadIdx.x; it < 400; it += 256){
    int ly = it / 20, lx = it % 20;
    int gy = oy - 2 + ly, gx = ox - 2 + lx;
    float v = 0.f;
    if (gy >= 0 && gy < 256 && gx >= 0 && gx < 256)
      v = (rdf<DT>(x, xbase + (gy<<8) + gx) - mean) / sd;
    xs[it] = v;
  }
  float wl1[9], wt1[9], wl2[9], wt2[9];
  #pragma unroll
  for (int k = 0; k < 9; k++){
    wl1[k] = rdf<DT>(la1w, c*9+k); wt1[k] = rdf<DT>(ta1w, c*9+k);
    wl2[k] = rdf<DT>(la2w, c*9+k); wt2[k] = rdf<DT>(ta2w, c*9+k);
  }
  float bl1 = rdf<DT>(la1b, c), bt1 = rdf<DT>(ta1b, c);
  __syncthreads();
  for (int it = threadIdx.x; it < 324; it += 256){
    int ly = it / 18, lx = it % 18;
    int cy = oy - 1 + ly, cx = ox - 1 + lx;
    float a1 = 0.f, a2 = 0.f;
    if (cy >= 0 && cy < 256 && cx >= 0 && cx < 256){
      a1 = bl1; a2 = bt1;
      #pragma unroll
      for (int dy = 0; dy < 3; dy++)
        #pragma unroll
        for (int dx = 0; dx < 3; dx++){
          float v = xs[(ly+dy)*20 + lx+dx];
          a1 += v * wl1[dy*3+dx]; a2 += v * wt1[dy*3+dx];
        }
      a1 = fmaxf(a1, 0.f); a2 = fmaxf(a2, 0.f);
    }
    ts[it] = a1; us[it] = a2;
  }
  __syncthreads();
  int ty = threadIdx.x >> 4, tx0 = threadIdx.x & 15;
  float l = rdf<DT>(la2b, c), t = rdf<DT>(ta2b, c);
  #pragma unroll
  for (int dy = 0; dy < 3; dy++)
    #pragma unroll
    for (int dx = 0; dx < 3; dx++){
      l += ts[(ty+dy)*18 + tx0+dx] * wl2[dy*3+dx];
      t += us[(ty+dy)*18 + tx0+dx] * wt2[dy*3+dx];
    }
  float v = xs[(ty+2)*20 + tx0+2];
  float r = v*(rdf<DT>(agnw,c)*stats[8+bc]) + (rdf<DT>(agnb,c) + stats[392+bc]) + l + t;
  xn2[xbase + ((oy+ty)<<8) + ox + tx0] = f2b(r);
}

// ---------- K5: mega window kernel ----------
// LDS arena 64512 B:
//  [0,27648)      xs[144][96]bf16  -> (compact) xc[64][96]bf16 @[0,12288) -> cs[64][96]bf16 @[0,12288)
//  [12288,24576)  Ks[64][96]bf16   (written after xs dead)
//  [24576,36864)  Vs[64][96]bf16
//  [36864,64512)  Qs[144][96]bf16  -> os[64][97]f32 (24832 B) after dw5
template<int DT>
__global__ __launch_bounds__(256) void k_attn_mega(const bf16* __restrict__ xn2,
    const void* qw, const void* qb, const void* kvw, const void* kvb,
    const void* dww, const void* dwb, const void* pw, const void* pb,
    const void* lsin, const float* __restrict__ biasT,
    const void* __restrict__ xin, const float* __restrict__ stats,
    void* __restrict__ outp, const int* __restrict__ flag){
  if (*flag != DT) return;
  __shared__ __align__(16) char smem[64512];
  bf16*  xs = (bf16*)smem;
  bf16*  xc = (bf16*)smem;
  bf16*  Ks = (bf16*)(smem + 12288);
  bf16*  Vs = (bf16*)(smem + 24576);
  bf16*  Qs = (bf16*)(smem + 36864);
  bf16*  cs = (bf16*)smem;
  float* os = (float*)(smem + 36864);
  int tid = threadIdx.x, wid = blockIdx.x;
  int b = wid >> 10, wy = (wid >> 5) & 31, wx = wid & 31;

  // 1. stage xn2 reflected 12x12 halo
  for (int it = tid; it < 13824; it += 256){
    int t = it % 144, c = it / 144;
    int ty = (wy<<3) - 2 + t/12, tx = (wx<<3) - 2 + t%12;
    ty = ty < 0 ? -ty : (ty > 255 ? 510 - ty : ty);
    tx = tx < 0 ? -tx : (tx > 255 ? 510 - tx : tx);
    xs[t*96 + c] = xn2[(((size_t)(b*96 + c))<<16) + (ty<<8) + tx];
  }
  __syncthreads();

  // 2. Q at 144 positions
  for (int it = tid; it < 13824; it += 256){
    int t = it % 144, oc = it / 144;
    const bf16* xr = xs + t*96;
    float a0=0.f,a1=0.f,a2=0.f,a3=0.f;
    size_t wb = (size_t)oc*96;
    #pragma unroll 4
    for (int cI = 0; cI < 96; cI += 4){
      a0 += b2f(xr[cI  ])*rdf<DT>(qw, wb+cI  );
      a1 += b2f(xr[cI+1])*rdf<DT>(qw, wb+cI+1);
      a2 += b2f(xr[cI+2])*rdf<DT>(qw, wb+cI+2);
      a3 += b2f(xr[cI+3])*rdf<DT>(qw, wb+cI+3);
    }
    Qs[t*96 + oc] = f2b(a0+a1+a2+a3 + rdf<DT>(qb, oc));
  }
  __syncthreads();

  // 3. compact xs center 8x8 -> xc (read-all, barrier, write)
  {
    bf16 tmp[24];
    #pragma unroll
    for (int k = 0; k < 24; k++){
      int it = tid + k*256;            // 6144 = 64*96
      int n = it & 63, c = it >> 6;
      int t = ((n>>3)+2)*12 + (n&7) + 2;
      tmp[k] = xs[t*96 + c];
    }
    __syncthreads();
    #pragma unroll
    for (int k = 0; k < 24; k++){
      int it = tid + k*256;
      int n = it & 63, c = it >> 6;
      xc[n*96 + c] = tmp[k];
    }
  }
  __syncthreads();

  // 4. K (x SCALE) and V at 64 positions
  for (int it = tid; it < 12288; it += 256){
    int n = it & 63, oc = it >> 6;
    const bf16* xr = xc + n*96;
    float a0=0.f,a1=0.f,a2=0.f,a3=0.f;
    size_t wb = (size_t)oc*96;
    #pragma unroll 4
    for (int cI = 0; cI < 96; cI += 4){
      a0 += b2f(xr[cI  ])*rdf<DT>(kvw, wb+cI  );
      a1 += b2f(xr[cI+1])*rdf<DT>(kvw, wb+cI+1);
      a2 += b2f(xr[cI+2])*rdf<DT>(kvw, wb+cI+2);
      a3 += b2f(xr[cI+3])*rdf<DT>(kvw, wb+cI+3);
    }
    float r = a0+a1+a2+a3 + rdf<DT>(kvb, oc);
    if (oc < 96) Ks[n*96 + oc] = f2b(r * SCALE_F);
    else         Vs[n*96 + oc - 96] = f2b(r);
  }
  __syncthreads();

  // 5. 5x5 dwconv on Q -> cs (cs region = dead xc)
  for (int it = tid; it < 6144; it += 256){
    int n = it & 63, c = it >> 6;
    int ty0 = (n>>3)+2, tx0 = (n&7)+2;
    float a = rdf<DT>(dwb, c);
    #pragma unroll
    for (int dy = -2; dy <= 2; dy++)
      #pragma unroll
      for (int dx = -2; dx <= 2; dx++)
        a += b2f(Qs[((ty0+dy)*12 + tx0+dx)*96 + c]) * rdf<DT>(dww, c*25 + (dy+2)*5 + dx+2);
    cs[n*96 + c] = f2b(a);
  }
  __syncthreads();

  // 6. attention (os region = dead Qs)
  if (tid < 192){
    int h = tid >> 6, n = tid & 63;
    float q[32];
    #pragma unroll
    for (int d = 0; d < 32; d++) q[d] = b2f(cs[n*96 + h*32 + d]);
    float ls = __expf(fminf(rdf<DT>(lsin, 0), LOGIT_MAX_F));
    const float* bh = biasT + h*4096 + n;
    float mx = -3e38f, s = 0.f;
    float o[32];
    #pragma unroll
    for (int d = 0; d < 32; d++) o[d] = 0.f;
    for (int m = 0; m < 64; m++){
      const bf16* kr = Ks + m*96 + h*32;
      float c0=0.f,c1=0.f,c2=0.f,c3=0.f;
      #pragma unroll
      for (int d = 0; d < 32; d += 4){
        c0 += q[d  ]*b2f(kr[d  ]); c1 += q[d+1]*b2f(kr[d+1]);
        c2 += q[d+2]*b2f(kr[d+2]); c3 += q[d+3]*b2f(kr[d+3]);
      }
      float l = (c0+c1+c2+c3)*ls + bh[m*64];
      float nm = fmaxf(mx, l);
      float corr = __expf(mx - nm);
      float p = __expf(l - nm);
      s = s*corr + p;
      const bf16* vr = Vs + m*96 + h*32;
      #pragma unroll
      for (int d = 0; d < 32; d++) o[d] = o[d]*corr + p*b2f(vr[d]);
      mx = nm;
    }
    float inv = 1.f / s;
    #pragma unroll
    for (int d = 0; d < 32; d++) os[n*97 + h*32 + d] = o[d]*inv;
  }
  __syncthreads();

  // 7. proj + residual -> out
  for (int it = tid; it < 6144; it += 256){
    int n = it & 63, oc = it >> 6;
    const float* orow = os + n*97;
    float a0=0.f,a1=0.f,a2=0.f,a3=0.f;
    size_t wb = (size_t)oc*96;
    #pragma unroll 4
    for (int cI = 0; cI < 96; cI += 4){
      a0 += orow[cI  ]*rdf<DT>(pw, wb+cI  );
      a1 += orow[cI+1]*rdf<DT>(pw, wb+cI+1);
      a2 += orow[cI+2]*rdf<DT>(pw, wb+cI+2);
      a3 += orow[cI+3]*rdf<DT>(pw, wb+cI+3);
    }
    int gy = (wy<<3) + (n>>3), gx = (wx<<3) + (n&7);
    size_t gi = (((size_t)(b*96 + oc))<<16) + (gy<<8) + gx;
    float x1 = rdf<DT>(xin, gi) + (a0+a1+a2+a3 + rdf<DT>(pb, oc))*stats[8 + b*96 + oc]
             + stats[392 + b*96 + oc];
    wrf<DT>(outp, gi, x1);
  }
}

// ---------- K6: fused MLP in-place on d_out ----------
template<int DT>
__global__ __launch_bounds__(256) void k_mlp_fused(void* __restrict__ io,
    const void* w1, const void* b1, const void* w2, const void* b2v,
    const int* __restrict__ flag){
  if (*flag != DT) return;
  __shared__ bf16 x1s[6144];    // [c][64]
  __shared__ bf16 hs[24576];    // [k][64]
  int blk = blockIdx.x; int b = blk >> 10; int pix0 = (blk & 1023) << 6;
  int tid = threadIdx.x;
  for (int it = tid; it < 6144; it += 256){
    int c = it >> 6, pp = it & 63;
    x1s[it] = f2b(rdf<DT>(io, (((size_t)(b*96 + c))<<16) + pix0 + pp));
  }
  __syncthreads();
  for (int it = tid; it < 24576; it += 256){
    int oc = it >> 6, pp = it & 63;
    size_t wb = (size_t)oc*96;
    float a0=0.f,a1=0.f,a2=0.f,a3=0.f;
    #pragma unroll 4
    for (int c = 0; c < 96; c += 4){
      a0 += b2f(x1s[(c  )*64 + pp])*rdf<DT>(w1, wb+c  );
      a1 += b2f(x1s[(c+1)*64 + pp])*rdf<DT>(w1, wb+c+1);
      a2 += b2f(x1s[(c+2)*64 + pp])*rdf<DT>(w1, wb+c+2);
      a3 += b2f(x1s[(c+3)*64 + pp])*rdf<DT>(w1, wb+c+3);
    }
    hs[it] = f2b(fmaxf(a0+a1+a2+a3 + rdf<DT>(b1, oc), 0.f));
  }
  __syncthreads();
  for (int it = tid; it < 6144; it += 256){
    int oc = it >> 6, pp = it & 63;
    size_t wb = (size_t)oc*384;
    float a0=0.f,a1=0.f,a2=0.f,a3=0.f;
    #pragma unroll 4
    for (int k = 0; k < 384; k += 4){
      a0 += b2f(hs[(k  )*64 + pp])*rdf<DT>(w2, wb+k  );
      a1 += b2f(hs[(k+1)*64 + pp])*rdf<DT>(w2, wb+k+1);
      a2 += b2f(hs[(k+2)*64 + pp])*rdf<DT>(w2, wb+k+2);
      a3 += b2f(hs[(k+3)*64 + pp])*rdf<DT>(w2, wb+k+3);
    }
    wrf<DT>(io, (((size_t)(b*96 + oc))<<16) + pix0 + pp,
            b2f(x1s[oc*64 + pp]) + a0+a1+a2+a3 + rdf<DT>(b2v, oc));
  }
}

extern "C" void kernel_launch(void* const* d_in, const int* in_sizes, int n_in,
                              void* d_out, int out_size, void* d_ws, size_t ws_size,
                              hipStream_t stream) {
  const void* x      = d_in[0];
  const void* agnw   = d_in[1];
  const void* agnb   = d_in[2];
  const void* meta1w = d_in[3];
  const void* meta1b = d_in[4];
  const void* meta2w = d_in[5];
  const void* meta2b = d_in[6];
  const void* la1w   = d_in[7];
  const void* la1b   = d_in[8];
  const void* la2w   = d_in[9];
  const void* la2b   = d_in[10];
  const void* ta1w   = d_in[11];
  const void* ta1b   = d_in[12];
  const void* ta2w   = d_in[13];
  const void* ta2b   = d_in[14];
  const void* qw     = d_in[15];
  const void* qb     = d_in[16];
  const void* kvw    = d_in[17];
  const void* kvb    = d_in[18];
  const void* dww    = d_in[19];
  const void* dwb    = d_in[20];
  const void* pw     = d_in[21];
  const void* pb     = d_in[22];
  const void* lsin   = d_in[23];
  const void* rpw1   = d_in[24];
  const void* rpb1   = d_in[25];
  const void* rpw2   = d_in[26];
  const void* rpb2   = d_in[27];
  const void* m1w    = d_in[28];
  const void* m1b    = d_in[29];
  const void* m2w    = d_in[30];
  const void* m2b    = d_in[31];

  // ws: flag @0 | partials @256 (8KB) | stats @8448 (3.1KB) | biasT @12288 (48KB) | xn2 @65536 (48MB)
  char* ws = (char*)d_ws;
  int*   flag     = (int*)ws;
  float* partials = (float*)(ws + 256);
  float* stats    = (float*)(ws + 8448);
  float* biasT    = (float*)(ws + 12288);
  bf16*  xn2      = (bf16*)(ws + 65536);

  k_detect<<<1, 256, 0, stream>>>(x, flag);

  // bf16 variant
  k_stats_partial<0><<<1024, 256, 0, stream>>>(x, partials, flag);
  k_stats_final<0>  <<<1,    256, 0, stream>>>(partials, meta1w, meta1b, meta2w, meta2b, stats, flag);
  k_bias<0>         <<<4096, 256, 0, stream>>>(rpw1, rpb1, rpw2, rpb2, biasT, flag);
  k_agn_fused<0>    <<<98304,256, 0, stream>>>(x, stats, la1w, la1b, la2w, la2b,
                                               ta1w, ta1b, ta2w, ta2b, agnw, agnb, xn2, flag);
  k_attn_mega<0>    <<<4096, 256, 0, stream>>>(xn2, qw, qb, kvw, kvb, dww, dwb, pw, pb,
                                               lsin, biasT, x, stats, d_out, flag);
  k_mlp_fused<0>    <<<4096, 256, 0, stream>>>(d_out, m1w, m1b, m2w, m2b, flag);

  // fp32 variant
  k_stats_partial<1><<<1024, 256, 0, stream>>>(x, partials, flag);
  k_stats_final<1>  <<<1,    256, 0, stream>>>(partials, meta1w, meta1b, meta2w, meta2b, stats, flag);
  k_bias<1>         <<<4096, 256, 0, stream>>>(rpw1, rpb1, rpw2, rpb2, biasT, flag);
  k_agn_fused<1>    <<<98304,256, 0, stream>>>(x, stats, la1w, la1b, la2w, la2b,
                                               ta1w, ta1b, ta2w, ta2b, agnw, agnb, xn2, flag);
  k_attn_mega<1>    <<<4096, 256, 0, stream>>>(xn2, qw, qb, kvw, kvb, dww, dwb, pw, pb,
                                               lsin, biasT, x, stats, d_out, flag);
  k_mlp_fused<1>    <<<4096, 256, 0, stream>>>(d_out, m1w, m1b, m2w, m2b, flag);
}

// Round 4
// 5068.658 us; speedup vs baseline: 1.0095x; 1.0095x over previous
//
#include <hip/hip_runtime.h>
#include <hip/hip_bf16.h>

typedef __hip_bfloat16 bf16;

#define PER_B     6291456            // 96*65536
#define S_EL      25165824u          // 4*PER_B
#define EPS_F     1e-5f
#define SCALE_F   0.17677669529663687f   // 32^-0.5
#define LOGIT_MAX_F 4.605170185988092f   // log(100)

__device__ __forceinline__ float b2f(bf16 v){ return __bfloat162float(v); }
__device__ __forceinline__ bf16  f2b(float v){ return __float2bfloat16(v); }

// DT=0: buffers are bf16.  DT=1: buffers are fp32.
template<int DT> __device__ __forceinline__ float rdf(const void* p, size_t i){
  return DT ? ((const float*)p)[i] : b2f(((const bf16*)p)[i]);
}
template<int DT> __device__ __forceinline__ void wrf(void* p, size_t i, float v){
  if (DT) ((float*)p)[i] = v; else ((bf16*)p)[i] = f2b(v);
}
// paired weight load (i must be even)
template<int DT> __device__ __forceinline__ float2 rd2(const void* p, size_t i){
  if (DT) return *(const float2*)((const float*)p + i);
  unsigned u = *(const unsigned*)((const bf16*)p + i);
  return make_float2(__uint_as_float(u << 16), __uint_as_float(u & 0xffff0000u));
}

// ---------- K0: dtype detector ----------
__global__ __launch_bounds__(256) void k_detect(const void* __restrict__ x, int* __restrict__ flag){
  __shared__ int cnt;
  if (threadIdx.x == 0) cnt = 0;
  __syncthreads();
  float v = b2f(((const bf16*)x)[(size_t)threadIdx.x * 16]);
  int bad = (!(v == v)) || (fabsf(v) > 1e20f);
  if (bad) atomicAdd(&cnt, 1);
  __syncthreads();
  if (threadIdx.x == 0) *flag = (cnt >= 4) ? 1 : 0;
}

// ---------- K1: per-batch partial sums ----------
template<int DT>
__global__ __launch_bounds__(256) void k_stats_partial(const void* __restrict__ x,
    float* __restrict__ partials, const int* __restrict__ flag){
  if (*flag != DT) return;
  int blk = blockIdx.x;
  int b = blk >> 8, chunk = blk & 255;
  const int chunkN = PER_B / 256;
  size_t base = (size_t)b * PER_B + (size_t)chunk * chunkN;
  float s = 0.f, ss = 0.f;
  for (int i = threadIdx.x; i < chunkN; i += 256){
    float v = rdf<DT>(x, base + i); s += v; ss += v*v;
  }
  __shared__ float sh[512];
  sh[threadIdx.x] = s; sh[256 + threadIdx.x] = ss;
  __syncthreads();
  for (int st = 128; st > 0; st >>= 1){
    if (threadIdx.x < st){
      sh[threadIdx.x]     += sh[threadIdx.x + st];
      sh[256+threadIdx.x] += sh[256+threadIdx.x + st];
    }
    __syncthreads();
  }
  if (threadIdx.x == 0){ partials[blk*2] = sh[0]; partials[blk*2+1] = sh[256]; }
}

// ---------- K2: finalize mean/std + rescale/rebias ----------
// stats: [0..3]=mean, [4..7]=std, [8..391]=rescale[b*96+c], [392..775]=rebias
template<int DT>
__global__ __launch_bounds__(256) void k_stats_final(const float* __restrict__ partials,
    const void* m1w, const void* m1b, const void* m2w, const void* m2b,
    float* __restrict__ stats, const int* __restrict__ flag){
  if (*flag != DT) return;
  __shared__ float sh[512];
  __shared__ float mS[4], sS[4];
  for (int b = 0; b < 4; b++){
    sh[threadIdx.x]     = partials[(b*256+threadIdx.x)*2];
    sh[256+threadIdx.x] = partials[(b*256+threadIdx.x)*2+1];
    __syncthreads();
    for (int st = 128; st > 0; st >>= 1){
      if (threadIdx.x < st){
        sh[threadIdx.x]     += sh[threadIdx.x + st];
        sh[256+threadIdx.x] += sh[256+threadIdx.x + st];
      }
      __syncthreads();
    }
    if (threadIdx.x == 0){
      float mean = sh[0] / (float)PER_B;
      float var  = sh[256] / (float)PER_B - mean*mean;
      float stdv = sqrtf(var + EPS_F);
      mS[b] = mean; sS[b] = stdv;
      stats[b] = mean; stats[4+b] = stdv;
    }
    __syncthreads();
  }
  for (int t = threadIdx.x; t < 384; t += 256){
    int b = t / 96, c = t % 96;
    stats[8+t]   = sS[b]*rdf<DT>(m1w,c) + rdf<DT>(m1b,c);
    stats[392+t] = mS[b]*rdf<DT>(m2w,c) + rdf<DT>(m2b,c);
  }
}

// ---------- K3: rel-pos bias table, transposed [h][m][n] ----------
template<int DT>
__global__ __launch_bounds__(256) void k_bias(const void* w1, const void* b1v,
    const void* w2, const void* b2v, float* __restrict__ biasT, const int* __restrict__ flag){
  if (*flag != DT) return;
  int i = blockIdx.x >> 6, j = blockIdx.x & 63;   // i = query n, j = key m
  int dy = (i>>3) - (j>>3), dx = (i&7) - (j&7);
  float fy = (float)dy, fx = (float)dx;
  float r0 = copysignf(log1pf(fabsf(fy)), fy);
  float r1 = copysignf(log1pf(fabsf(fx)), fx);
  int t = threadIdx.x;
  float hb = fmaxf(r0*rdf<DT>(w1,t*2) + r1*rdf<DT>(w1,t*2+1) + rdf<DT>(b1v,t), 0.f);
  __shared__ float sh[256];
  for (int h = 0; h < 3; h++){
    sh[t] = hb * rdf<DT>(w2, h*256+t);
    __syncthreads();
    for (int st = 128; st > 0; st >>= 1){ if (t < st) sh[t] += sh[t+st]; __syncthreads(); }
    if (t == 0) biasT[h*4096 + j*64 + i] = sh[0] + rdf<DT>(b2v, h);
    __syncthreads();
  }
}

// ---------- K4: fused AGN: x -> xn2 (bf16) ----------
template<int DT>
__global__ __launch_bounds__(256) void k_agn_fused(const void* __restrict__ x,
    const float* __restrict__ stats,
    const void* la1w, const void* la1b, const void* la2w, const void* la2b,
    const void* ta1w, const void* ta1b, const void* ta2w, const void* ta2b,
    const void* agnw, const void* agnb,
    bf16* __restrict__ xn2, const int* __restrict__ flag){
  if (*flag != DT) return;
  __shared__ float xs[400];   // 20x20 zero-padded
  __shared__ float ts[324];   // 18x18
  __shared__ float us[324];
  int idx = blockIdx.x;
  int tile = idx & 255; int bc = idx >> 8; int c = bc % 96; int b = bc / 96;
  int oy = (tile >> 4) << 4, ox = (tile & 15) << 4;
  float mean = stats[b], sd = stats[4+b];
  size_t xbase = ((size_t)bc) << 16;
  for (int it = threadIdx.x; it < 400; it += 256){
    int ly = it / 20, lx = it % 20;
    int gy = oy - 2 + ly, gx = ox - 2 + lx;
    float v = 0.f;
    if (gy >= 0 && gy < 256 && gx >= 0 && gx < 256)
      v = (rdf<DT>(x, xbase + (gy<<8) + gx) - mean) / sd;
    xs[it] = v;
  }
  float wl1[9], wt1[9], wl2[9], wt2[9];
  #pragma unroll
  for (int k = 0; k < 9; k++){
    wl1[k] = rdf<DT>(la1w, c*9+k); wt1[k] = rdf<DT>(ta1w, c*9+k);
    wl2[k] = rdf<DT>(la2w, c*9+k); wt2[k] = rdf<DT>(ta2w, c*9+k);
  }
  float bl1 = rdf<DT>(la1b, c), bt1 = rdf<DT>(ta1b, c);
  __syncthreads();
  for (int it = threadIdx.x; it < 324; it += 256){
    int ly = it / 18, lx = it % 18;
    int cy = oy - 1 + ly, cx = ox - 1 + lx;
    float a1 = 0.f, a2 = 0.f;
    if (cy >= 0 && cy < 256 && cx >= 0 && cx < 256){
      a1 = bl1; a2 = bt1;
      #pragma unroll
      for (int dy = 0; dy < 3; dy++)
        #pragma unroll
        for (int dx = 0; dx < 3; dx++){
          float v = xs[(ly+dy)*20 + lx+dx];
          a1 += v * wl1[dy*3+dx]; a2 += v * wt1[dy*3+dx];
        }
      a1 = fmaxf(a1, 0.f); a2 = fmaxf(a2, 0.f);
    }
    ts[it] = a1; us[it] = a2;
  }
  __syncthreads();
  int ty = threadIdx.x >> 4, tx0 = threadIdx.x & 15;
  float l = rdf<DT>(la2b, c), t = rdf<DT>(ta2b, c);
  #pragma unroll
  for (int dy = 0; dy < 3; dy++)
    #pragma unroll
    for (int dx = 0; dx < 3; dx++){
      l += ts[(ty+dy)*18 + tx0+dx] * wl2[dy*3+dx];
      t += us[(ty+dy)*18 + tx0+dx] * wt2[dy*3+dx];
    }
  float v = xs[(ty+2)*20 + tx0+2];
  float r = v*(rdf<DT>(agnw,c)*stats[8+bc]) + (rdf<DT>(agnb,c) + stats[392+bc]) + l + t;
  xn2[xbase + ((oy+ty)<<8) + ox + tx0] = f2b(r);
}

// ---------- K5: mega window kernel, transposed conflict-free LDS ----------
// Arena 64512 B, all tiles [channel][pixel] with pixel = lane index:
//  [0,27648)      xs[96][144] -> xc[96][64] @[0,12288) -> cs[96][64] @[0,12288)
//  [12288,24576)  Ks[96][64]  (written after xs compacted)
//  [24576,36864)  Vs[96][64]
//  [36864,64512)  Qs[96][144] -> os[96][64]f32 @[36864,61440) after dw5
template<int DT>
__global__ __launch_bounds__(256) void k_attn_mega(const bf16* __restrict__ xn2,
    const void* qw, const void* qb, const void* kvw, const void* kvb,
    const void* dww, const void* dwb, const void* pw, const void* pb,
    const void* lsin, const float* __restrict__ biasT,
    const void* __restrict__ xin, const float* __restrict__ stats,
    void* __restrict__ outp, const int* __restrict__ flag){
  if (*flag != DT) return;
  __shared__ __align__(16) char smem[64512];
  bf16*  xs = (bf16*)smem;              // [96][144]
  bf16*  xc = (bf16*)smem;              // [96][64] compacted
  bf16*  cs = (bf16*)smem;              // [96][64] (xc dead after KV)
  bf16*  Ks = (bf16*)(smem + 12288);    // [96][64]
  bf16*  Vs = (bf16*)(smem + 24576);    // [96][64]
  bf16*  Qs = (bf16*)(smem + 36864);    // [96][144]
  float* os = (float*)(smem + 36864);   // [96][64] f32 (Qs dead after dw5)
  int tid = threadIdx.x, wid = blockIdx.x;
  int b = wid >> 10, wy = (wid >> 5) & 31, wx = wid & 31;
  int wv = tid >> 6, ln = tid & 63;

  // 1. stage xn2 reflected 12x12 halo -> xs[c][t]
  for (int it = tid; it < 13824; it += 256){
    int t = it % 144, c = it / 144;
    int ty = (wy<<3) - 2 + t/12, tx = (wx<<3) - 2 + t%12;
    ty = ty < 0 ? -ty : (ty > 255 ? 510 - ty : ty);
    tx = tx < 0 ? -tx : (tx > 255 ? 510 - tx : tx);
    xs[c*144 + t] = xn2[(((size_t)(b*96 + c))<<16) + (ty<<8) + tx];
  }
  __syncthreads();

  // 2. Q at 144 positions: wave owns 24 oc; 3 pixels/lane share each weight pair
  for (int ocb = 0; ocb < 24; ocb++){
    int oc = wv*24 + ocb;
    size_t wb = (size_t)oc*96;
    float a0 = 0.f, a1 = 0.f, a2 = 0.f;
    #pragma unroll 4
    for (int c = 0; c < 96; c += 2){
      float2 w = rd2<DT>(qw, wb + c);
      const bf16* r0 = xs + c*144;
      const bf16* r1 = xs + (c+1)*144;
      a0 += w.x * b2f(r0[ln]);
      a1 += w.x * b2f(r0[64 + ln]);
      a2 += w.x * b2f(r0[128 + (ln & 15)]);
      a0 += w.y * b2f(r1[ln]);
      a1 += w.y * b2f(r1[64 + ln]);
      a2 += w.y * b2f(r1[128 + (ln & 15)]);
    }
    float qbv = rdf<DT>(qb, oc);
    Qs[oc*144 + ln]      = f2b(a0 + qbv);
    Qs[oc*144 + 64 + ln] = f2b(a1 + qbv);
    if (ln < 16) Qs[oc*144 + 128 + ln] = f2b(a2 + qbv);
  }
  __syncthreads();

  // 3. compact xs centers -> xc[c][n] (reg-buffered, regions overlap)
  {
    bf16 tmp[24];
    #pragma unroll
    for (int k = 0; k < 24; k++){
      int it = tid + k*256;
      int n = it & 63, c = it >> 6;
      int t = ((n>>3)+2)*12 + (n&7) + 2;
      tmp[k] = xs[c*144 + t];
    }
    __syncthreads();
    #pragma unroll
    for (int k = 0; k < 24; k++){
      int it = tid + k*256;
      int n = it & 63, c = it >> 6;
      xc[c*64 + n] = tmp[k];
    }
  }
  __syncthreads();

  // 4. K (x SCALE) and V: wave owns 48 oc, lane = pixel
  for (int ocb = 0; ocb < 48; ocb++){
    int oc = wv*48 + ocb;
    size_t wb = (size_t)oc*96;
    float a = 0.f;
    #pragma unroll 4
    for (int c = 0; c < 96; c += 2){
      float2 w = rd2<DT>(kvw, wb + c);
      a += w.x * b2f(xc[c*64 + ln]);
      a += w.y * b2f(xc[(c+1)*64 + ln]);
    }
    a += rdf<DT>(kvb, oc);
    if (oc < 96) Ks[oc*64 + ln] = f2b(a * SCALE_F);
    else         Vs[(oc-96)*64 + ln] = f2b(a);
  }
  __syncthreads();

  // 5. 5x5 dwconv on Q -> cs[c][n]: wave owns 24 channels, lane = pixel
  {
    int ty0 = (ln>>3)+2, tx0 = (ln&7)+2;
    for (int cb = 0; cb < 24; cb++){
      int c = wv*24 + cb;
      float a = rdf<DT>(dwb, c);
      const bf16* Qrow = Qs + c*144;
      #pragma unroll
      for (int dy = -2; dy <= 2; dy++)
        #pragma unroll
        for (int dx = -2; dx <= 2; dx++)
          a += b2f(Qrow[(ty0+dy)*12 + tx0+dx]) * rdf<DT>(dww, c*25 + (dy+2)*5 + dx+2);
      cs[c*64 + ln] = f2b(a);
    }
  }
  __syncthreads();

  // 6. attention: wave = head, lane = token; K/V reads are lane-broadcast
  if (tid < 192){
    int h = wv, n = ln;
    float q[32];
    #pragma unroll
    for (int d = 0; d < 32; d++) q[d] = b2f(cs[(h*32 + d)*64 + n]);
    float ls = __expf(fminf(rdf<DT>(lsin, 0), LOGIT_MAX_F));
    const float* bh = biasT + h*4096 + n;
    float mx = -3e38f, s = 0.f;
    float o[32];
    #pragma unroll
    for (int d = 0; d < 32; d++) o[d] = 0.f;
    for (int m = 0; m < 64; m++){
      float c0=0.f,c1=0.f,c2=0.f,c3=0.f;
      #pragma unroll
      for (int d = 0; d < 32; d += 4){
        c0 += q[d  ]*b2f(Ks[(h*32+d  )*64 + m]);
        c1 += q[d+1]*b2f(Ks[(h*32+d+1)*64 + m]);
        c2 += q[d+2]*b2f(Ks[(h*32+d+2)*64 + m]);
        c3 += q[d+3]*b2f(Ks[(h*32+d+3)*64 + m]);
      }
      float l = (c0+c1+c2+c3)*ls + bh[m*64];
      float nm = fmaxf(mx, l);
      float corr = __expf(mx - nm);
      float p = __expf(l - nm);
      s = s*corr + p;
      #pragma unroll
      for (int d = 0; d < 32; d++) o[d] = o[d]*corr + p*b2f(Vs[(h*32+d)*64 + m]);
      mx = nm;
    }
    float inv = 1.f / s;
    #pragma unroll
    for (int d = 0; d < 32; d++) os[(h*32 + d)*64 + n] = o[d]*inv;
  }
  __syncthreads();

  // 7. proj + residual -> out: wave owns 24 oc, lane = pixel
  for (int ocb = 0; ocb < 24; ocb++){
    int oc = wv*24 + ocb;
    size_t wb = (size_t)oc*96;
    float a = 0.f;
    #pragma unroll 4
    for (int c = 0; c < 96; c += 2){
      float2 w = rd2<DT>(pw, wb + c);
      a += w.x * os[c*64 + ln];
      a += w.y * os[(c+1)*64 + ln];
    }
    a += rdf<DT>(pb, oc);
    int gy = (wy<<3) + (ln>>3), gx = (wx<<3) + (ln&7);
    size_t gi = (((size_t)(b*96 + oc))<<16) + (gy<<8) + gx;
    float x1 = rdf<DT>(xin, gi) + a*stats[8 + b*96 + oc] + stats[392 + b*96 + oc];
    wrf<DT>(outp, gi, x1);
  }
}

// ---------- K6: fused MLP in-place on d_out, paired weights ----------
template<int DT>
__global__ __launch_bounds__(256) void k_mlp_fused(void* __restrict__ io,
    const void* w1, const void* b1, const void* w2, const void* b2v,
    const int* __restrict__ flag){
  if (*flag != DT) return;
  __shared__ bf16 x1s[6144];    // [c][64]
  __shared__ bf16 hs[24576];    // [k][64]
  int blk = blockIdx.x; int b = blk >> 10; int pix0 = (blk & 1023) << 6;
  int tid = threadIdx.x, wv = tid >> 6, pp = tid & 63;
  for (int it = tid; it < 6144; it += 256){
    int c = it >> 6, q = it & 63;
    x1s[it] = f2b(rdf<DT>(io, (((size_t)(b*96 + c))<<16) + pix0 + q));
  }
  __syncthreads();
  // fc1: wave owns 96 oc, lane = pixel
  for (int ocb = 0; ocb < 96; ocb++){
    int oc = wv*96 + ocb;
    size_t wb = (size_t)oc*96;
    float a = 0.f;
    #pragma unroll 4
    for (int c = 0; c < 96; c += 2){
      float2 w = rd2<DT>(w1, wb + c);
      a += w.x * b2f(x1s[c*64 + pp]);
      a += w.y * b2f(x1s[(c+1)*64 + pp]);
    }
    hs[oc*64 + pp] = f2b(fmaxf(a + rdf<DT>(b1, oc), 0.f));
  }
  __syncthreads();
  // fc2: wave owns 24 oc, lane = pixel
  for (int ocb = 0; ocb < 24; ocb++){
    int oc = wv*24 + ocb;
    size_t wb = (size_t)oc*384;
    float a = 0.f;
    #pragma unroll 4
    for (int k = 0; k < 384; k += 2){
      float2 w = rd2<DT>(w2, wb + k);
      a += w.x * b2f(hs[k*64 + pp]);
      a += w.y * b2f(hs[(k+1)*64 + pp]);
    }
    wrf<DT>(io, (((size_t)(b*96 + oc))<<16) + pix0 + pp,
            b2f(x1s[oc*64 + pp]) + a + rdf<DT>(b2v, oc));
  }
}

extern "C" void kernel_launch(void* const* d_in, const int* in_sizes, int n_in,
                              void* d_out, int out_size, void* d_ws, size_t ws_size,
                              hipStream_t stream) {
  const void* x      = d_in[0];
  const void* agnw   = d_in[1];
  const void* agnb   = d_in[2];
  const void* meta1w = d_in[3];
  const void* meta1b = d_in[4];
  const void* meta2w = d_in[5];
  const void* meta2b = d_in[6];
  const void* la1w   = d_in[7];
  const void* la1b   = d_in[8];
  const void* la2w   = d_in[9];
  const void* la2b   = d_in[10];
  const void* ta1w   = d_in[11];
  const void* ta1b   = d_in[12];
  const void* ta2w   = d_in[13];
  const void* ta2b   = d_in[14];
  const void* qw     = d_in[15];
  const void* qb     = d_in[16];
  const void* kvw    = d_in[17];
  const void* kvb    = d_in[18];
  const void* dww    = d_in[19];
  const void* dwb    = d_in[20];
  const void* pw     = d_in[21];
  const void* pb     = d_in[22];
  const void* lsin   = d_in[23];
  const void* rpw1   = d_in[24];
  const void* rpb1   = d_in[25];
  const void* rpw2   = d_in[26];
  const void* rpb2   = d_in[27];
  const void* m1w    = d_in[28];
  const void* m1b    = d_in[29];
  const void* m2w    = d_in[30];
  const void* m2b    = d_in[31];

  // ws: flag @0 | partials @256 | stats @8448 | biasT @12288 | xn2 @65536 (48MB)
  char* ws = (char*)d_ws;
  int*   flag     = (int*)ws;
  float* partials = (float*)(ws + 256);
  float* stats    = (float*)(ws + 8448);
  float* biasT    = (float*)(ws + 12288);
  bf16*  xn2      = (bf16*)(ws + 65536);

  k_detect<<<1, 256, 0, stream>>>(x, flag);

  // bf16 variant
  k_stats_partial<0><<<1024, 256, 0, stream>>>(x, partials, flag);
  k_stats_final<0>  <<<1,    256, 0, stream>>>(partials, meta1w, meta1b, meta2w, meta2b, stats, flag);
  k_bias<0>         <<<4096, 256, 0, stream>>>(rpw1, rpb1, rpw2, rpb2, biasT, flag);
  k_agn_fused<0>    <<<98304,256, 0, stream>>>(x, stats, la1w, la1b, la2w, la2b,
                                               ta1w, ta1b, ta2w, ta2b, agnw, agnb, xn2, flag);
  k_attn_mega<0>    <<<4096, 256, 0, stream>>>(xn2, qw, qb, kvw, kvb, dww, dwb, pw, pb,
                                               lsin, biasT, x, stats, d_out, flag);
  k_mlp_fused<0>    <<<4096, 256, 0, stream>>>(d_out, m1w, m1b, m2w, m2b, flag);

  // fp32 variant
  k_stats_partial<1><<<1024, 256, 0, stream>>>(x, partials, flag);
  k_stats_final<1>  <<<1,    256, 0, stream>>>(partials, meta1w, meta1b, meta2w, meta2b, stats, flag);
  k_bias<1>         <<<4096, 256, 0, stream>>>(rpw1, rpb1, rpw2, rpb2, biasT, flag);
  k_agn_fused<1>    <<<98304,256, 0, stream>>>(x, stats, la1w, la1b, la2w, la2b,
                                               ta1w, ta1b, ta2w, ta2b, agnw, agnb, xn2, flag);
  k_attn_mega<1>    <<<4096, 256, 0, stream>>>(xn2, qw, qb, kvw, kvb, dww, dwb, pw, pb,
                                               lsin, biasT, x, stats, d_out, flag);
  k_mlp_fused<1>    <<<4096, 256, 0, stream>>>(d_out, m1w, m1b, m2w, m2b, flag);
}